// Round 5
// baseline (1208.469 us; speedup 1.0000x reference)
//
#include <hip/hip_runtime.h>

#define BATCH 65536
#define NF 16

typedef __bf16 bf16;
typedef bf16 bf16x4 __attribute__((ext_vector_type(4)));
typedef bf16 bf16x8 __attribute__((ext_vector_type(8)));
typedef float f32x4 __attribute__((ext_vector_type(4)));

// tanh with PRE-SCALED matmul: acc = (2/ln2)*(W u + b)  ->  z = 1 - 2/(exp2(acc)+1)
// rcp(inf)=0 and exp2(-big)=0 make the +/-large cases exact.
__device__ __forceinline__ float tanh_ps(float s) {
  float e = exp2f(s);
  return 1.0f - 2.0f * __builtin_amdgcn_rcpf(e + 1.0f);
}

__device__ __forceinline__ bf16x4 cvt4(f32x4 v) {
  return bf16x4{(bf16)v[0], (bf16)v[1], (bf16)v[2], (bf16)v[3]};
}
__device__ __forceinline__ f32x4 up4(bf16x4 v) {
  return f32x4{(float)v[0], (float)v[1], (float)v[2], (float)v[3]};
}

// D[batch][feat] = mfma(A=u_frag, B=W_frag). 256 thr / 16 batch rows / block.
// Wave w owns feature tiles {2w,2w+1}; ONE af read set (4 x b128) shared by
// both tiles -> device LDS-read traffic halved vs 1-tile/wave. Double-buffered
// u, 1 barrier/geval. k1/k2 kept as packed bf16x4 (register diet: target
// 5 waves/SIMD via __launch_bounds__(256,5)).
//
// LDS A-layout, ROW-PERMUTATION swizzle (16 rows + pad 17):
//   element (row,c) at idx8 = (c>>3)*17 + perm(row), elem = idx8*8 + (c&7)
//   perm(row): b3b2b1b0 -> b0 + 2*b2 + 4*b3 + 8*b1 (bijective)
// Writes (thread owns rows quad*4+r, 2 fixed feats): banks 8*quad+4*c3+c21
//   -> all 32 banks, 2 lanes/bank (same dword) = conflict-free.
// Reads: row 'col' -> scat(col) per-thread constant.
__global__ __launch_bounds__(256, 5) void node_kernel(
    const float* __restrict__ x,
    const float* __restrict__ W0, const float* __restrict__ b0,
    const float* __restrict__ W1, const float* __restrict__ b1,
    const float* __restrict__ Wode, const float* __restrict__ bode,
    float* __restrict__ out)
{
  __shared__ __align__(16) bf16 Au[2][2176];   // 16 cblocks * 17 rows * 8

  const int tid  = threadIdx.x;
  const int lane = tid & 63;
  const int w    = tid >> 6;   // wave 0..3
  const int col  = lane & 15;
  const int quad = lane >> 4;
  const int rowBase = blockIdx.x * 16;

  const float C   = 2.8853900817779268f;   // 2/ln2
  const float dt  = 1.0f / 15.0f;
  const float dt3 = dt / 3.0f;
  const float e8  = dt * 0.125f;
  const float q8  = dt * dt * 0.125f;

  // read-side permuted row (per-thread constant)
  const int scat = (col & 1) + (((col >> 2) & 3) << 1) + (((col >> 1) & 1) << 3);
  // write-side r offsets (elems): perm contribution of r = (r&1)*8 + (r>>1)*64
  const int roff[4] = {0, 8, 64, 72};

  int  n[2], abase[2], obase[2];
  bool nok[2];
#pragma unroll
  for (int n2 = 0; n2 < 2; ++n2) {
    n[n2] = (w * 2 + n2) * 16 + col;
    nok[n2] = (n[n2] < 100);
    abase[n2] = ((n[n2] >> 3) * 17 + quad * 2) * 8 + (n[n2] & 7);
    obase[n2] = (rowBase + quad * 4) * (NF * 100) + n[n2];
  }

  // ---- W_ode B-fragments + biases, PRE-SCALED by 2/ln2 (persistent regs) ----
  bf16x8 bfo[2][4];
  float  biaso[2];
#pragma unroll
  for (int n2 = 0; n2 < 2; ++n2) {
    biaso[n2] = nok[n2] ? bode[n[n2]] * C : 0.0f;
#pragma unroll
    for (int kc = 0; kc < 4; ++kc)
#pragma unroll
      for (int j = 0; j < 8; ++j) {
        const int k = kc * 32 + quad * 8 + j;
        bfo[n2][kc][j] = (nok[n2] && k < 100) ? (bf16)(Wode[n[n2] * 100 + k] * C)
                                              : (bf16)0.0f;
      }
  }

  // ---- stage x into Au[0] (coalesced fp32 reads -> swizzled bf16 A-layout) ----
#pragma unroll 1
  for (int i = tid; i < 2048; i += 256) {
    const int r16 = i >> 7;
    const int c   = i & 127;
    const float v = (c < 100) ? x[(rowBase + r16) * 100 + c] : 0.0f;
    const int p = (r16 & 1) + (((r16 >> 2) & 3) << 1) + (((r16 >> 1) & 1) << 3);
    Au[0][((c >> 3) * 17 + p) * 8 + (c & 7)] = (bf16)v;
  }

  f32x4  y0a[2], y1a[2];     // [n2] : 4 batch rows x 1 feature each
  bf16x4 k1[2], k2[2];       // packed bf16 (register diet)

  // ---- init: y0 = x@W0^T + b0 ; y1 = x@W1^T + b1 ; seed Au[1]=y0 ; out t=0 ----
  {
    bf16x8 bf0[2][4], bf1[2][4];
    float bias0[2], bias1[2];
#pragma unroll
    for (int n2 = 0; n2 < 2; ++n2) {
      bias0[n2] = nok[n2] ? b0[n[n2]] : 0.0f;
      bias1[n2] = nok[n2] ? b1[n[n2]] : 0.0f;
#pragma unroll
      for (int kc = 0; kc < 4; ++kc)
#pragma unroll
        for (int j = 0; j < 8; ++j) {
          const int k = kc * 32 + quad * 8 + j;
          const bool ok = (nok[n2] && k < 100);
          bf0[n2][kc][j] = ok ? (bf16)W0[n[n2] * 100 + k] : (bf16)0.0f;
          bf1[n2][kc][j] = ok ? (bf16)W1[n[n2] * 100 + k] : (bf16)0.0f;
        }
    }

    __syncthreads();   // x staging visible

    bf16x8 af[4];
#pragma unroll
    for (int kc = 0; kc < 4; ++kc)
      af[kc] = *(const bf16x8*)&Au[0][((kc * 4 + quad) * 17 + scat) * 8];
#pragma unroll
    for (int n2 = 0; n2 < 2; ++n2) {
      f32x4 a0 = { bias0[n2], bias0[n2], bias0[n2], bias0[n2] };
      f32x4 a1 = { bias1[n2], bias1[n2], bias1[n2], bias1[n2] };
#pragma unroll
      for (int kc = 0; kc < 4; ++kc) {
        a0 = __builtin_amdgcn_mfma_f32_16x16x32_bf16(af[kc], bf0[n2][kc], a0, 0, 0, 0);
        a1 = __builtin_amdgcn_mfma_f32_16x16x32_bf16(af[kc], bf1[n2][kc], a1, 0, 0, 0);
      }
      y0a[n2] = a0;
      y1a[n2] = a1;
#pragma unroll
      for (int r = 0; r < 4; ++r) {
        Au[1][abase[n2] + roff[r]] = (bf16)a0[r];          // seed u = y0
        if (nok[n2]) out[obase[n2] + r * 1600] = a1[r];    // out[:,0,:] = s1
      }
    }
  }
  __syncthreads();   // seed visible

  // One geval: 4 shared af reads; per n-tile: 4 MFMA, tanh (pre-scaled), FOLD
  // (sets uw, may store out), swizzled write to Au[WR]. One barrier per geval.
#define GEVAL(RD, WR, ...) do {                                                 \
    bf16x8 af[4];                                                               \
    _Pragma("unroll")                                                           \
    for (int kc = 0; kc < 4; ++kc)                                              \
      af[kc] = *(const bf16x8*)&Au[RD][((kc * 4 + quad) * 17 + scat) * 8];      \
    _Pragma("unroll")                                                           \
    for (int n2 = 0; n2 < 2; ++n2) {                                            \
      f32x4 acc = { biaso[n2], biaso[n2], biaso[n2], biaso[n2] };               \
      _Pragma("unroll")                                                         \
      for (int kc = 0; kc < 4; ++kc)                                            \
        acc = __builtin_amdgcn_mfma_f32_16x16x32_bf16(af[kc], bfo[n2][kc],      \
                                                      acc, 0, 0, 0);            \
      f32x4 z;                                                                  \
      _Pragma("unroll")                                                         \
      for (int r = 0; r < 4; ++r) z[r] = tanh_ps(acc[r]);                       \
      f32x4 uw;                                                                 \
      __VA_ARGS__;                                                              \
      _Pragma("unroll")                                                         \
      for (int r = 0; r < 4; ++r)                                               \
        Au[WR][abase[n2] + roff[r]] = (bf16)uw[r];                              \
    }                                                                           \
    __syncthreads();                                                            \
  } while (0)

#pragma unroll 1
  for (int t = 1; t < NF; ++t) {
    const int ot = t * 100;

    // g1: k1 = g(y0); u2 = y0 + dt/3*k1
    GEVAL(1, 0, {
      k1[n2] = cvt4(z);
      uw = y0a[n2] + dt3 * z;
    });

    // g2: k2 = g(u2); u3 = y0 + dt*k2 - dt/3*k1
    GEVAL(0, 1, {
      k2[n2] = cvt4(z);
      uw = y0a[n2] + dt * z - dt3 * up4(k1[n2]);
    });

    // g3: k3 = g(u3); u4 = y0 + dt*(k1-k2+k3); fold y1, partial-fold y0; out[t]
    GEVAL(1, 0, {
      const f32x4 a   = up4(k1[n2]);
      const f32x4 b2  = up4(k2[n2]);
      const f32x4 y0v = y0a[n2];
      uw = y0v + dt * (a - b2 + z);
      const f32x4 ny1 = y1a[n2] + dt * y0v + q8 * (a + 2.0f * b2 + z);
      y1a[n2] = ny1;
      y0a[n2] = y0v + e8 * (a + 3.0f * (b2 + z));
      _Pragma("unroll")
      for (int r = 0; r < 4; ++r)
        if (nok[n2]) out[obase[n2] + r * 1600 + ot] = ny1[r];
    });

    // g4: k4 = g(u4); y0 += dt/8*k4; write y0 as next step's u
    GEVAL(0, 1, {
      const f32x4 y0v = y0a[n2] + e8 * z;
      y0a[n2] = y0v;
      uw = y0v;
    });
  }
#undef GEVAL
}

extern "C" void kernel_launch(void* const* d_in, const int* in_sizes, int n_in,
                              void* d_out, int out_size, void* d_ws, size_t ws_size,
                              hipStream_t stream) {
  (void)in_sizes; (void)n_in; (void)out_size; (void)d_ws; (void)ws_size;
  const float* x    = (const float*)d_in[0];
  const float* W0   = (const float*)d_in[1];
  const float* b0   = (const float*)d_in[2];
  const float* W1   = (const float*)d_in[3];
  const float* b1   = (const float*)d_in[4];
  const float* Wode = (const float*)d_in[5];
  const float* bode = (const float*)d_in[6];
  float* out = (float*)d_out;

  dim3 grid(BATCH / 16), block(256);
  hipLaunchKernelGGL(node_kernel, grid, block, 0, stream,
                     x, W0, b0, W1, b1, Wode, bode, out);
}

// Round 6
// 683.113 us; speedup vs baseline: 1.7691x; 1.7691x over previous
//
#include <hip/hip_runtime.h>

#define BATCH 65536
#define NF 16

typedef __bf16 bf16;
typedef bf16 bf16x8 __attribute__((ext_vector_type(8)));
typedef float f32x4 __attribute__((ext_vector_type(4)));

// tanh with PRE-SCALED matmul: acc = (2/ln2)*(W u + b) -> tanh = 1 - 2/(exp2(acc)+1)
// rcp(inf)=0 and exp2(-big)=0 make the +/-large cases exact.
__device__ __forceinline__ float tanh_ps(float s) {
  float e = exp2f(s);
  return 1.0f - 2.0f * __builtin_amdgcn_rcpf(e + 1.0f);
}

// Proven R3 structure (364 us measured): D[batch][feat] = mfma(A=u_frag, B=W_frag).
//  - u in LDS, MFMA A-fragment layout, element (row r64, col c) at
//      idx8 = (c>>3)*65 + r64   (pad 64->65), elem = idx8*8 + (c&7)
//    DOUBLE-BUFFERED: each geval reads Au[RD], writes Au[WR], ONE barrier.
//  - 8 waves (512 thr): wave w owns feature tile [16w,16w+16); loops 4 row-tiles.
//  - 64 batch rows/block (REQUIRED: 16-row blocks trigger L2 partial-line churn,
//    FETCH 14MB->954MB measured; keep >=32 rows and grid <=2048).
//  - Out stores: scalar f32, lanes cover 16 consecutive features x 4 rows
//    -> full 64B segments per instruction (clean write path).
//  - NEW vs R3: W_ode/b_ode pre-scaled by 2/ln2 -> MFMA output feeds exp2
//    directly (kills 16 v_mul per thread per geval).
__global__ __launch_bounds__(512, 4) void node_kernel(
    const float* __restrict__ x,
    const float* __restrict__ W0, const float* __restrict__ b0,
    const float* __restrict__ W1, const float* __restrict__ b1,
    const float* __restrict__ Wode, const float* __restrict__ bode,
    float* __restrict__ out)
{
  __shared__ __align__(16) bf16 Au[2][8320];

  const int tid  = threadIdx.x;
  const int lane = tid & 63;
  const int w    = tid >> 6;   // wave 0..7
  const int col  = lane & 15;
  const int quad = lane >> 4;
  const int rowBase = blockIdx.x * 64;

  const float C   = 2.8853900817779268f;   // 2/ln2
  const float dt  = 1.0f / 15.0f;
  const float dt3 = dt / 3.0f;
  const float e8  = dt * 0.125f;
  const float q8  = dt * dt * 0.125f;

  const int  n    = w * 16 + col;                       // this lane's feature (D col)
  const bool nok  = (n < 100);
  const int  abase = ((n >> 3) * 65 + quad * 4) * 8 + (n & 7);  // LDS elem base (scatter)
  const int  obase = (rowBase + quad * 4) * (NF * 100) + n;     // out elem base

  // ---- W_ode B-fragments + bias, PRE-SCALED by 2/ln2 (persistent registers) ----
  bf16x8 bfo[4];
  const float biaso = nok ? bode[n] * C : 0.0f;
#pragma unroll
  for (int kc = 0; kc < 4; ++kc)
#pragma unroll
    for (int j = 0; j < 8; ++j) {
      const int k = kc * 32 + quad * 8 + j;
      bfo[kc][j] = (nok && k < 100) ? (bf16)(Wode[n * 100 + k] * C) : (bf16)0.0f;
    }

  // ---- stage x into Au[0] (coalesced fp32 reads -> bf16 A-layout), pad=0 ----
#pragma unroll 1
  for (int i = tid; i < 8192; i += 512) {
    const int r64 = i >> 7;
    const int c   = i & 127;
    const float v = (c < 100) ? x[(rowBase + r64) * 100 + c] : 0.0f;
    Au[0][((c >> 3) * 65 + r64) * 8 + (c & 7)] = (bf16)v;
  }

  f32x4 y0a[4], y1a[4], k1[4], k2[4];

  // ---- init: y0 = x@W0^T + b0 ; y1 = x@W1^T + b1 ; seed Au[1]=y0 ; out t=0 ----
  {
    bf16x8 bf0[4], bf1[4];
    const float bias0 = nok ? b0[n] : 0.0f;
    const float bias1 = nok ? b1[n] : 0.0f;
#pragma unroll
    for (int kc = 0; kc < 4; ++kc)
#pragma unroll
      for (int j = 0; j < 8; ++j) {
        const int k = kc * 32 + quad * 8 + j;
        const bool ok = (nok && k < 100);
        bf0[kc][j] = ok ? (bf16)W0[n * 100 + k] : (bf16)0.0f;
        bf1[kc][j] = ok ? (bf16)W1[n * 100 + k] : (bf16)0.0f;
      }

    __syncthreads();   // x staging visible

#pragma unroll
    for (int rt = 0; rt < 4; ++rt) {
      bf16x8 af[4];
#pragma unroll
      for (int kc = 0; kc < 4; ++kc)
        af[kc] = *(const bf16x8*)&Au[0][((kc * 4 + quad) * 65 + rt * 16 + col) * 8];
      f32x4 a0 = { bias0, bias0, bias0, bias0 };
      f32x4 a1 = { bias1, bias1, bias1, bias1 };
#pragma unroll
      for (int kc = 0; kc < 4; ++kc) {
        a0 = __builtin_amdgcn_mfma_f32_16x16x32_bf16(af[kc], bf0[kc], a0, 0, 0, 0);
        a1 = __builtin_amdgcn_mfma_f32_16x16x32_bf16(af[kc], bf1[kc], a1, 0, 0, 0);
      }
      y0a[rt] = a0;
      y1a[rt] = a1;
#pragma unroll
      for (int r = 0; r < 4; ++r) {
        Au[1][abase + rt * 128 + r * 8] = (bf16)a0[r];   // seed u = y0 (other buffer)
        if (nok) out[obase + rt * 25600 + r * 1600] = a1[r];
      }
    }
  }
  __syncthreads();   // seed visible

  // One geval: read u-frags from Au[RD], MFMA (pre-scaled), tanh, FOLD (sets uw,
  // may store out), write u' to Au[WR]. Single barrier; parity compile-time.
#define GEVAL(RD, WR, ...) do {                                                 \
    _Pragma("unroll")                                                           \
    for (int rt = 0; rt < 4; ++rt) {                                            \
      bf16x8 af[4];                                                             \
      _Pragma("unroll")                                                         \
      for (int kc = 0; kc < 4; ++kc)                                            \
        af[kc] = *(const bf16x8*)&Au[RD][((kc * 4 + quad) * 65 + rt * 16 + col) * 8]; \
      f32x4 acc = { biaso, biaso, biaso, biaso };                               \
      _Pragma("unroll")                                                         \
      for (int kc = 0; kc < 4; ++kc)                                            \
        acc = __builtin_amdgcn_mfma_f32_16x16x32_bf16(af[kc], bfo[kc], acc, 0, 0, 0); \
      f32x4 z;                                                                  \
      _Pragma("unroll")                                                         \
      for (int r = 0; r < 4; ++r) z[r] = tanh_ps(acc[r]);                       \
      f32x4 uw;                                                                 \
      __VA_ARGS__;                                                              \
      _Pragma("unroll")                                                         \
      for (int r = 0; r < 4; ++r)                                               \
        Au[WR][abase + rt * 128 + r * 8] = (bf16)uw[r];                         \
    }                                                                           \
    __syncthreads();                                                            \
  } while (0)

#pragma unroll 1
  for (int t = 1; t < NF; ++t) {
    const int ot = t * 100;

    // g1: k1 = g(y0); u2 = y0 + dt/3*k1
    GEVAL(1, 0, {
      k1[rt] = z;
      uw = y0a[rt] + dt3 * z;
    });

    // g2: k2 = g(u2); u3 = y0 + dt*k2 - dt/3*k1
    GEVAL(0, 1, {
      k2[rt] = z;
      uw = y0a[rt] + dt * z - dt3 * k1[rt];
    });

    // g3: k3 = g(u3); u4 = y0 + dt*(k1-k2+k3); fold y1, partial-fold y0; out[t]
    GEVAL(1, 0, {
      const f32x4 a   = k1[rt];
      const f32x4 b2  = k2[rt];
      const f32x4 y0v = y0a[rt];
      uw = y0v + dt * (a - b2 + z);
      const f32x4 ny1 = y1a[rt] + dt * y0v + q8 * (a + 2.0f * b2 + z);
      y1a[rt] = ny1;
      y0a[rt] = y0v + e8 * (a + 3.0f * (b2 + z));
      _Pragma("unroll")
      for (int r = 0; r < 4; ++r)
        if (nok) out[obase + rt * 25600 + r * 1600 + ot] = ny1[r];
    });

    // g4: k4 = g(u4); y0 += dt/8*k4; write y0 as next step's u
    GEVAL(0, 1, {
      const f32x4 y0v = y0a[rt] + e8 * z;
      y0a[rt] = y0v;
      uw = y0v;
    });
  }
#undef GEVAL
}

extern "C" void kernel_launch(void* const* d_in, const int* in_sizes, int n_in,
                              void* d_out, int out_size, void* d_ws, size_t ws_size,
                              hipStream_t stream) {
  (void)in_sizes; (void)n_in; (void)out_size; (void)d_ws; (void)ws_size;
  const float* x    = (const float*)d_in[0];
  const float* W0   = (const float*)d_in[1];
  const float* b0   = (const float*)d_in[2];
  const float* W1   = (const float*)d_in[3];
  const float* b1   = (const float*)d_in[4];
  const float* Wode = (const float*)d_in[5];
  const float* bode = (const float*)d_in[6];
  float* out = (float*)d_out;

  dim3 grid(BATCH / 64), block(512);
  hipLaunchKernelGGL(node_kernel, grid, block, 0, stream,
                     x, W0, b0, W1, b1, Wode, bode, out);
}